// Round 11
// baseline (169.384 us; speedup 1.0000x reference)
//
#include <hip/hip_runtime.h>
#include <hip/hip_bf16.h>

// DenseAttention — reassociated (6.44 GF vs 155 GF direct), bf16 MFMA.
// Round 11: cut the dispatch chain 5 -> 4 (r7/r9/r10 all ~142-148 despite very
// different kernel bodies => chain/fixed overhead dominates, not bodies).
//   gram: Gp[s][bq] = X^T X over u-half s   grid(16,8,2)=256, K=1024,
//         NON-atomic (no memset needed) + each block zeroes 8KB of Wt
//         (stream order makes gram a barrier before 2b's atomics).
//   2a:   Tt[ba][g][qf] = comb_g . (Gp0+Gp1)_f  grid(16,32)=512
//         (B-stager sums the two partials in f32, then converts)
//   2b:   Wt[ba][g][e] += Tt_g . qw_e      grid(16,8,4)=512, split-K4, atomic
//   out:  out[t][ag]   = x_t . Wt_g        grid(128,8)=1024
// All patterns r10-verified; only gram's split/zero duty and 2a's sum-stager
// are new. ws (14 MB): Gp 4 | Wt 2 | Tt 8.

typedef unsigned short u16;
using short8  = __attribute__((ext_vector_type(8))) short;
using floatx4 = __attribute__((ext_vector_type(4))) float;

__device__ inline u16 f2bf(float f) {               // RNE f32->bf16
    unsigned u = __float_as_uint(f);
    unsigned r = u + 0x7fffu + ((u >> 16) & 1u);
    return (u16)(r >> 16);
}

// Row-major source [64 m][64 k] (k-contiguous) -> fragment-major LDS (MT=4).
// Element (m,k): lane=((k&31)>>3)*16+(m&15), j=k&7,
// chunk=((k>>5)*4+(m>>4))*64+lane.
template <typename T>
__device__ inline void stage64(const T* __restrict__ src, long ld,
                               u16* __restrict__ dst, int tid) {
#pragma unroll
    for (int it = 0; it < 4; ++it) {
        const int flat = (it * 256 + tid) * 4;
        const int kl = flat & 63, rl = flat >> 6;
        ushort4 v;
        if (sizeof(T) == 4) {
            const float4 f = *(const float4*)&((const float*)src)[(long)rl * ld + kl];
            v.x = f2bf(f.x); v.y = f2bf(f.y); v.z = f2bf(f.z); v.w = f2bf(f.w);
        } else {
            v = *(const ushort4*)&((const u16*)src)[(long)rl * ld + kl];
        }
        const int chunk = ((kl >> 5) * 4 + (rl >> 4)) * 64 + ((kl >> 3) & 3) * 16 + (rl & 15);
        *(ushort4*)&dst[chunk * 8 + (kl & 7)] = v;
    }
}

// Same, but source = sum of two f32 partial arrays (same ld, stride apart).
__device__ inline void stage64_sum2(const float* __restrict__ s0,
                                    const float* __restrict__ s1, long ld,
                                    u16* __restrict__ dst, int tid) {
#pragma unroll
    for (int it = 0; it < 4; ++it) {
        const int flat = (it * 256 + tid) * 4;
        const int kl = flat & 63, rl = flat >> 6;
        const float4 f = *(const float4*)&s0[(long)rl * ld + kl];
        const float4 g = *(const float4*)&s1[(long)rl * ld + kl];
        ushort4 v;
        v.x = f2bf(f.x + g.x); v.y = f2bf(f.y + g.y);
        v.z = f2bf(f.z + g.z); v.w = f2bf(f.w + g.w);
        const int chunk = ((kl >> 5) * 4 + (rl >> 4)) * 64 + ((kl >> 3) & 3) * 16 + (rl & 15);
        *(ushort4*)&dst[chunk * 8 + (kl & 7)] = v;
    }
}

// K-major f32 source [64 k][64 m] (m-contiguous, row stride ld) -> fragment-
// major LDS (MT=4), scatter writes (round-6/10-verified pattern).
__device__ inline void stage_km64(const float* __restrict__ src, long ld,
                                  u16* __restrict__ dst, int tid) {
#pragma unroll
    for (int it = 0; it < 4; ++it) {
        const int flat = (it * 256 + tid) * 4;
        const int m = flat & 63, k = flat >> 6;
        const float4 f = *(const float4*)&src[(long)k * ld + m];
        const int cb_ = ((k >> 5) * 4 + (m >> 4)) * 64 + ((k & 31) >> 3) * 16 + (m & 15);
        const int j = k & 7;
        dst[(cb_ + 0) * 8 + j] = f2bf(f.x);
        dst[(cb_ + 1) * 8 + j] = f2bf(f.y);
        dst[(cb_ + 2) * 8 + j] = f2bf(f.z);
        dst[(cb_ + 3) * 8 + j] = f2bf(f.w);
    }
}

// C[m0+..64, n0+..64] (+)= A . B^T. 4 waves, wave w -> 32x32 at
// (IA=(w&1)*2, JB=(w>>1)*2) 16-tiles. AKM/BKM: K-major f32 source.
// BSUM2: B staged as f32 sum of B and B+partStride.
template <typename TA, typename TB, bool AKM, bool BKM, bool BSUM2, bool ATOMIC>
__device__ inline void gemm_tile(const TA* __restrict__ A, long lda,
                                 const TB* __restrict__ B, long ldb,
                                 long partStride,
                                 float* __restrict__ C, long ldc,
                                 int K, int m0, int n0) {
    __shared__ u16 As[4096];   // 8 KB
    __shared__ u16 Bs[4096];
    const int tid = threadIdx.x, lane = tid & 63, w = tid >> 6;
    const int IA = (w & 1) * 2, JB = (w >> 1) * 2;
    floatx4 acc[2][2] = {};

    for (int k0 = 0; k0 < K; k0 += 64) {
        if (AKM) stage_km64((const float*)A + (long)k0 * lda, lda, As, tid);
        else     stage64(A + k0, lda, As, tid);
        if (BSUM2) stage64_sum2((const float*)B + k0,
                                (const float*)B + partStride + k0, ldb, Bs, tid);
        else if (BKM) stage_km64((const float*)B + (long)k0 * ldb, ldb, Bs, tid);
        else     stage64(B + k0, ldb, Bs, tid);
        __syncthreads();
#pragma unroll
        for (int s = 0; s < 2; ++s) {
            short8 af[2], bfr[2];
#pragma unroll
            for (int i = 0; i < 2; ++i)
                af[i] = *(const short8*)&As[((s * 4 + IA + i) * 64 + lane) * 8];
#pragma unroll
            for (int j = 0; j < 2; ++j)
                bfr[j] = *(const short8*)&Bs[((s * 4 + JB + j) * 64 + lane) * 8];
#pragma unroll
            for (int i = 0; i < 2; ++i)
#pragma unroll
                for (int j = 0; j < 2; ++j)
                    acc[i][j] = __builtin_amdgcn_mfma_f32_16x16x32_bf16(af[i], bfr[j], acc[i][j], 0, 0, 0);
        }
        __syncthreads();
    }
    const int rb = (lane >> 4) * 4, col = lane & 15;
#pragma unroll
    for (int i = 0; i < 2; ++i)
#pragma unroll
        for (int j = 0; j < 2; ++j)
#pragma unroll
            for (int r = 0; r < 4; ++r) {
                const int gm = m0 + (IA + i) * 16 + rb + r;
                const int gn = n0 + (JB + j) * 16 + col;
                float* p = &C[(long)gm * ldc + gn];
                if (ATOMIC) atomicAdd(p, acc[i][j][r]); else *p = acc[i][j][r];
            }
}

// gram: Gp[split][bq][f][h] = sum_{u in half} x[b][u][qf] * x[b][u][qh]
// (non-atomic; also zeroes this block's 8KB slice of Wt — consumed 2 kernels
//  later, stream order guarantees visibility)
__global__ __launch_bounds__(256) void k_gram(const float* __restrict__ x,
                                              float* __restrict__ Gp,
                                              float* __restrict__ Wt) {
    const int tile = blockIdx.x, bq = blockIdx.y, split = blockIdx.z;
    const int tm = tile >> 2, tn = tile & 3;
    const int b = bq >> 2, q = bq & 3;
    {   // zero Wt slice: 256 blocks x 2048 floats
        const int bl = tile + 16 * bq + 128 * split;
        float4 zero = {0.f, 0.f, 0.f, 0.f};
        float4* wz = (float4*)Wt + (long)bl * 512 + threadIdx.x * 2;
        wz[0] = zero; wz[1] = zero;
    }
    const float* base = x + (long)b * 2097152 + (long)split * 1024 * 1024 + q * 256;
    gemm_tile<float, float, true, true, false, false>(
        base + tm * 64, 1024,
        base + tn * 64, 1024, 0,
        Gp + (long)(split * 8 + bq) * 65536, 256,
        1024, tm * 64, tn * 64);
}

// 2a: Tt[ba][g][q*256+f] = sum_h comb[a][q*256+h][g] * (Gp0+Gp1)[bq][f][h]
__global__ __launch_bounds__(256) void k_2a(const float* __restrict__ comb,
                                            const float* __restrict__ Gp,
                                            float* __restrict__ Tt) {
    const int tile = blockIdx.x, i = blockIdx.y;     // i = ba*4+q
    const int tm = tile >> 2, tn = tile & 3;
    const int q = i & 3, ba = i >> 2, b = ba >> 2, a = ba & 3;
    gemm_tile<float, float, true, false, true, false>(
        comb + (long)a * 262144 + (long)q * 256 * 256 + tm * 64, 256,
        Gp + (long)(b * 4 + q) * 65536 + (long)tn * 64 * 256, 256,
        (long)8 * 65536,
        Tt + (long)ba * 262144, 1024,
        256, tm * 64, q * 256 + tn * 64);
}

// 2b: Wt[ba][g][e] += sum_{k in split} Tt[ba][g][k] * qw[a][e][k]
__global__ __launch_bounds__(256) void k_2b(const float* __restrict__ Tt,
                                            const float* __restrict__ qw,
                                            float* __restrict__ Wt) {
    const int tile = blockIdx.x, ba = blockIdx.y, split = blockIdx.z;
    const int tm = tile >> 2, tn = tile & 3;
    const int a = ba & 3;
    gemm_tile<float, float, false, false, false, true>(
        Tt + (long)ba * 262144 + (long)tm * 64 * 1024 + split * 256, 1024,
        qw + (long)a * 262144 + (long)tn * 64 * 1024 + split * 256, 1024, 0,
        Wt + (long)ba * 65536, 256,
        256, tm * 64, tn * 64);
}

// out: out[b][t][a*256+g] = sum_e x[b][t][a*256+e] * Wt[ba][g][e]
__global__ __launch_bounds__(256) void k_3(const float* __restrict__ x,
                                           const float* __restrict__ Wt,
                                           float* __restrict__ out) {
    const int tl = blockIdx.x, ba = blockIdx.y;      // tl: tm 0..31, tn 0..3
    const int tm = tl >> 2, tn = tl & 3;
    const int b = ba >> 2, a = ba & 3;
    gemm_tile<float, float, false, false, false, false>(
        x + (long)b * 2097152 + (long)tm * 64 * 1024 + a * 256, 1024,
        Wt + (long)ba * 65536 + (long)tn * 64 * 256, 256, 0,
        out + (long)b * 2097152 + a * 256, 1024,
        256, tm * 64, tn * 64);
}

extern "C" void kernel_launch(void* const* d_in, const int* in_sizes, int n_in,
                              void* d_out, int out_size, void* d_ws, size_t ws_size,
                              hipStream_t stream) {
    const float* x    = (const float*)d_in[0];   // [2,2048,1024]
    const float* qw   = (const float*)d_in[1];   // [4,256,1024]
    const float* comb = (const float*)d_in[2];   // [4,1024,256]
    float* out = (float*)d_out;

    char* ws = (char*)d_ws;
    float* Gp = (float*)(ws);                    // 4 MB [2][8][256x256] gram partials
    float* Wt = (float*)(ws + (4u << 20));       // 2 MB [8][256][256]  Wt[g][e]
    float* Tt = (float*)(ws + (6u << 20));       // 8 MB [8][256][1024] Tt[g][qf]

    k_gram<<<dim3(16, 8, 2), 256, 0, stream>>>(x, Gp, Wt);
    k_2a  <<<dim3(16, 32),   256, 0, stream>>>(comb, Gp, Tt);
    k_2b  <<<dim3(16, 8, 4), 256, 0, stream>>>(Tt, qw, Wt);
    k_3   <<<dim3(128, 8),   256, 0, stream>>>(x, Wt, out);
}

// Round 12
// 140.405 us; speedup vs baseline: 1.2064x; 1.2064x over previous
//
#include <hip/hip_runtime.h>
#include <hip/hip_bf16.h>

// DenseAttention — reassociated (6.44 GF vs 155 GF direct), bf16 MFMA.
// Round 12: r10 structure (best 4-GEMM config) + single-barrier bodies.
// r11 showed bodies are barrier/iteration-latency-bound (gram: 50us, 7.3M LDS
// conflict cycles, 1.4% MfmaUtil at 1 blk/CU x 16 iters x 2 barriers). Fix:
// stage ALL of K=256 (4 x 64-k fragment blocks, 32KB/operand) in one burst,
// ONE __syncthreads, 32 MFMA/wave, store. 8 sync points -> 1; 16 global loads
// per thread in flight at once (HBM latency paid once).
//   memset: zero G+Wt (4 MB)
//   gram:  G[bq][f][h] += x_f . x_h       grid(16,8,8)=1024, split-K8, atomic
//   2a:    Tt[ba][g][qf] = comb_g . G_f   grid(16,32)=512
//   2b:    Wt[ba][g][e] += Tt_g . qw_e    grid(16,8,4)=512, split-K4, atomic
//   out:   out[t][ag]   = x_t . Wt_g      grid(128,8)=1024
// LDS 64KB/block -> 2 blocks/CU. All stores/atomics coalesced. Fragment-major
// LDS -> conflict-free ds_read_b128 fragment reads. ws (12 MB): G 2|Wt 2|Tt 8.

typedef unsigned short u16;
using short8  = __attribute__((ext_vector_type(8))) short;
using floatx4 = __attribute__((ext_vector_type(4))) float;

__device__ inline u16 f2bf(float f) {               // RNE f32->bf16
    unsigned u = __float_as_uint(f);
    unsigned r = u + 0x7fffu + ((u >> 16) & 1u);
    return (u16)(r >> 16);
}

// Row-major source [64 m][64 k] (k-contiguous) -> fragment-major LDS (MT=4).
// Element (m,k): lane=((k&31)>>3)*16+(m&15), j=k&7,
// chunk=((k>>5)*4+(m>>4))*64+lane.  dst = 4096-u16 fragment block.
template <typename T>
__device__ inline void stage64(const T* __restrict__ src, long ld,
                               u16* __restrict__ dst, int tid) {
#pragma unroll
    for (int it = 0; it < 4; ++it) {
        const int flat = (it * 256 + tid) * 4;
        const int kl = flat & 63, rl = flat >> 6;
        ushort4 v;
        if (sizeof(T) == 4) {
            const float4 f = *(const float4*)&((const float*)src)[(long)rl * ld + kl];
            v.x = f2bf(f.x); v.y = f2bf(f.y); v.z = f2bf(f.z); v.w = f2bf(f.w);
        } else {
            v = *(const ushort4*)&((const u16*)src)[(long)rl * ld + kl];
        }
        const int chunk = ((kl >> 5) * 4 + (rl >> 4)) * 64 + ((kl >> 3) & 3) * 16 + (rl & 15);
        *(ushort4*)&dst[chunk * 8 + (kl & 7)] = v;
    }
}

// K-major f32 source [64 k][64 m] (m-contiguous, row stride ld) -> fragment-
// major LDS (scatter writes; round-6/10-verified pattern).
__device__ inline void stage_km64(const float* __restrict__ src, long ld,
                                  u16* __restrict__ dst, int tid) {
#pragma unroll
    for (int it = 0; it < 4; ++it) {
        const int flat = (it * 256 + tid) * 4;
        const int m = flat & 63, k = flat >> 6;
        const float4 f = *(const float4*)&src[(long)k * ld + m];
        const int cb_ = ((k >> 5) * 4 + (m >> 4)) * 64 + ((k & 31) >> 3) * 16 + (m & 15);
        const int j = k & 7;
        dst[(cb_ + 0) * 8 + j] = f2bf(f.x);
        dst[(cb_ + 1) * 8 + j] = f2bf(f.y);
        dst[(cb_ + 2) * 8 + j] = f2bf(f.z);
        dst[(cb_ + 3) * 8 + j] = f2bf(f.w);
    }
}

// C[m0+..64, n0+..64] (+)= A . B^T, K = 256 in ONE staging burst + ONE barrier.
// 4 waves, wave w -> 32x32 at (IA=(w&1)*2, JB=(w>>1)*2) 16-tiles.
// AKM/BKM: operand staged from K-major f32 source.
template <typename TA, typename TB, bool AKM, bool BKM, bool ATOMIC>
__device__ inline void gemm_tile(const TA* __restrict__ A, long lda,
                                 const TB* __restrict__ B, long ldb,
                                 float* __restrict__ C, long ldc,
                                 int m0, int n0) {
    __shared__ u16 As[16384];   // 32 KB: 4 x 64-k fragment blocks
    __shared__ u16 Bs[16384];
    const int tid = threadIdx.x, lane = tid & 63, w = tid >> 6;
    const int IA = (w & 1) * 2, JB = (w >> 1) * 2;
    floatx4 acc[2][2] = {};

#pragma unroll
    for (int kb = 0; kb < 4; ++kb) {
        if (AKM) stage_km64((const float*)A + (long)(kb * 64) * lda, lda, As + kb * 4096, tid);
        else     stage64(A + kb * 64, lda, As + kb * 4096, tid);
    }
#pragma unroll
    for (int kb = 0; kb < 4; ++kb) {
        if (BKM) stage_km64((const float*)B + (long)(kb * 64) * ldb, ldb, Bs + kb * 4096, tid);
        else     stage64(B + kb * 64, ldb, Bs + kb * 4096, tid);
    }
    __syncthreads();

#pragma unroll
    for (int kb = 0; kb < 4; ++kb)
#pragma unroll
        for (int s = 0; s < 2; ++s) {
            short8 af[2], bfr[2];
#pragma unroll
            for (int i = 0; i < 2; ++i)
                af[i] = *(const short8*)&As[kb * 4096 + ((s * 4 + IA + i) * 64 + lane) * 8];
#pragma unroll
            for (int j = 0; j < 2; ++j)
                bfr[j] = *(const short8*)&Bs[kb * 4096 + ((s * 4 + JB + j) * 64 + lane) * 8];
#pragma unroll
            for (int i = 0; i < 2; ++i)
#pragma unroll
                for (int j = 0; j < 2; ++j)
                    acc[i][j] = __builtin_amdgcn_mfma_f32_16x16x32_bf16(af[i], bfr[j], acc[i][j], 0, 0, 0);
        }

    const int rb = (lane >> 4) * 4, col = lane & 15;
#pragma unroll
    for (int i = 0; i < 2; ++i)
#pragma unroll
        for (int j = 0; j < 2; ++j)
#pragma unroll
            for (int r = 0; r < 4; ++r) {
                const int gm = m0 + (IA + i) * 16 + rb + r;
                const int gn = n0 + (JB + j) * 16 + col;
                float* p = &C[(long)gm * ldc + gn];
                if (ATOMIC) atomicAdd(p, acc[i][j][r]); else *p = acc[i][j][r];
            }
}

// gram: G[bq][f][h] += sum_{u in split} x[b][u][qf] * x[b][u][qh]
__global__ __launch_bounds__(256) void k_gram(const float* __restrict__ x,
                                              float* __restrict__ G) {
    const int tile = blockIdx.x, bq = blockIdx.y, split = blockIdx.z;
    const int tm = tile >> 2, tn = tile & 3;
    const int b = bq >> 2, q = bq & 3;
    const float* base = x + (long)b * 2097152 + (long)split * 256 * 1024 + q * 256;
    gemm_tile<float, float, true, true, true>(
        base + tm * 64, 1024,
        base + tn * 64, 1024,
        G + (long)bq * 65536, 256,
        tm * 64, tn * 64);
}

// 2a: Tt[ba][g][q*256+f] = sum_h comb[a][q*256+h][g] * G[bq][f][h]
__global__ __launch_bounds__(256) void k_2a(const float* __restrict__ comb,
                                            const float* __restrict__ G,
                                            float* __restrict__ Tt) {
    const int tile = blockIdx.x, i = blockIdx.y;     // i = ba*4+q
    const int tm = tile >> 2, tn = tile & 3;
    const int q = i & 3, ba = i >> 2, b = ba >> 2, a = ba & 3;
    gemm_tile<float, float, true, false, false>(
        comb + (long)a * 262144 + (long)q * 256 * 256 + tm * 64, 256,
        G + (long)(b * 4 + q) * 65536 + (long)tn * 64 * 256, 256,
        Tt + (long)ba * 262144, 1024,
        tm * 64, q * 256 + tn * 64);
}

// 2b: Wt[ba][g][e] += sum_{k in split} Tt[ba][g][k] * qw[a][e][k]
__global__ __launch_bounds__(256) void k_2b(const float* __restrict__ Tt,
                                            const float* __restrict__ qw,
                                            float* __restrict__ Wt) {
    const int tile = blockIdx.x, ba = blockIdx.y, split = blockIdx.z;
    const int tm = tile >> 2, tn = tile & 3;
    const int a = ba & 3;
    gemm_tile<float, float, false, false, true>(
        Tt + (long)ba * 262144 + (long)tm * 64 * 1024 + split * 256, 1024,
        qw + (long)a * 262144 + (long)tn * 64 * 1024 + split * 256, 1024,
        Wt + (long)ba * 65536, 256,
        tm * 64, tn * 64);
}

// out: out[b][t][a*256+g] = sum_e x[b][t][a*256+e] * Wt[ba][g][e]
__global__ __launch_bounds__(256) void k_3(const float* __restrict__ x,
                                           const float* __restrict__ Wt,
                                           float* __restrict__ out) {
    const int tl = blockIdx.x, ba = blockIdx.y;      // tl: tm 0..31, tn 0..3
    const int tm = tl >> 2, tn = tl & 3;
    const int b = ba >> 2, a = ba & 3;
    gemm_tile<float, float, false, false, false>(
        x + (long)b * 2097152 + (long)tm * 64 * 1024 + a * 256, 1024,
        Wt + (long)ba * 65536 + (long)tn * 64 * 256, 256,
        out + (long)b * 2097152 + a * 256, 1024,
        tm * 64, tn * 64);
}

extern "C" void kernel_launch(void* const* d_in, const int* in_sizes, int n_in,
                              void* d_out, int out_size, void* d_ws, size_t ws_size,
                              hipStream_t stream) {
    const float* x    = (const float*)d_in[0];   // [2,2048,1024]
    const float* qw   = (const float*)d_in[1];   // [4,256,1024]
    const float* comb = (const float*)d_in[2];   // [4,1024,256]
    float* out = (float*)d_out;

    char* ws = (char*)d_ws;
    float* G  = (float*)(ws);                    // 2 MB [8][256x256] (G,Wt contiguous for memset)
    float* Wt = (float*)(ws + (2u << 20));       // 2 MB [8][256][256]  Wt[g][e]
    float* Tt = (float*)(ws + (4u << 20));       // 8 MB [8][256][1024] Tt[g][qf]

    hipMemsetAsync(d_ws, 0, 4u << 20, stream);   // zero G + Wt
    k_gram<<<dim3(16, 8, 8), 256, 0, stream>>>(x, G);
    k_2a  <<<dim3(16, 32),   256, 0, stream>>>(comb, G, Tt);
    k_2b  <<<dim3(16, 8, 4), 256, 0, stream>>>(Tt, qw, Wt);
    k_3   <<<dim3(128, 8),   256, 0, stream>>>(x, Wt, out);
}

// Round 13
// 138.120 us; speedup vs baseline: 1.2264x; 1.0165x over previous
//
#include <hip/hip_runtime.h>
#include <hip/hip_bf16.h>

// DenseAttention — reassociated (6.44 GF vs 155 GF direct), bf16 MFMA.
// Round 13: chain-shaving on r12 (best: 140.4us).
//   - memset dispatch deleted: gram is NON-atomic (writes 8 partials Gp, plain
//     coalesced stores -> no atomic drain) and zeroes Wt slices (2KB/block).
//   - 2a sums the 8 Gp partials in f32 in its B-stager (L2-hot), converts once.
//   - Tt stored as bf16 (2b converted it immediately anyway -> bitwise
//     identical downstream, half the traffic; 2b stager becomes a copy).
//   gram:  Gp[s][bq][f][h] = x_f . x_h     grid(16,8,8)=1024, K=256 one-burst
//   2a:    Tt[ba][g][qf] = comb_g . (sum_s Gp)_f  grid(16,32)=512, bf16 out
//   2b:    Wt[ba][g][e] += Tt_g . qw_e     grid(16,8,4)=512, split-K4, atomic
//   out:   out[t][ag]   = x_t . Wt_g       grid(128,8)=1024
// Bodies keep r12's single-barrier structure (stage all K=256, one sync,
// 32 MFMA/wave). Fragment-major LDS -> conflict-free ds_read_b128.
// ws (22 MB): Gp 16 | Wt 2 | Tt(bf16) 4.

typedef unsigned short u16;
using short8  = __attribute__((ext_vector_type(8))) short;
using floatx4 = __attribute__((ext_vector_type(4))) float;

__device__ inline u16 f2bf(float f) {               // RNE f32->bf16
    unsigned u = __float_as_uint(f);
    unsigned r = u + 0x7fffu + ((u >> 16) & 1u);
    return (u16)(r >> 16);
}

// Row-major source [64 m][64 k] (k-contiguous) -> fragment-major LDS (MT=4).
// Element (m,k): lane=((k&31)>>3)*16+(m&15), j=k&7,
// chunk=((k>>5)*4+(m>>4))*64+lane.  dst = one 4096-u16 fragment block.
template <typename T>
__device__ inline void stage64(const T* __restrict__ src, long ld,
                               u16* __restrict__ dst, int tid) {
#pragma unroll
    for (int it = 0; it < 4; ++it) {
        const int flat = (it * 256 + tid) * 4;
        const int kl = flat & 63, rl = flat >> 6;
        ushort4 v;
        if (sizeof(T) == 4) {
            const float4 f = *(const float4*)&((const float*)src)[(long)rl * ld + kl];
            v.x = f2bf(f.x); v.y = f2bf(f.y); v.z = f2bf(f.z); v.w = f2bf(f.w);
        } else {
            v = *(const ushort4*)&((const u16*)src)[(long)rl * ld + kl];
        }
        const int chunk = ((kl >> 5) * 4 + (rl >> 4)) * 64 + ((kl >> 3) & 3) * 16 + (rl & 15);
        *(ushort4*)&dst[chunk * 8 + (kl & 7)] = v;
    }
}

// Same, but source = f32 sum of 8 partial arrays spaced partStride apart.
__device__ inline void stage64_sum8(const float* __restrict__ s0, long ld,
                                    long partStride,
                                    u16* __restrict__ dst, int tid) {
#pragma unroll
    for (int it = 0; it < 4; ++it) {
        const int flat = (it * 256 + tid) * 4;
        const int kl = flat & 63, rl = flat >> 6;
        const long off = (long)rl * ld + kl;
        float4 acc = *(const float4*)&s0[off];
#pragma unroll
        for (int s = 1; s < 8; ++s) {
            const float4 f = *(const float4*)&s0[(long)s * partStride + off];
            acc.x += f.x; acc.y += f.y; acc.z += f.z; acc.w += f.w;
        }
        ushort4 v;
        v.x = f2bf(acc.x); v.y = f2bf(acc.y); v.z = f2bf(acc.z); v.w = f2bf(acc.w);
        const int chunk = ((kl >> 5) * 4 + (rl >> 4)) * 64 + ((kl >> 3) & 3) * 16 + (rl & 15);
        *(ushort4*)&dst[chunk * 8 + (kl & 7)] = v;
    }
}

// K-major f32 source [64 k][64 m] (m-contiguous, row stride ld) -> fragment-
// major LDS (scatter writes; round-6/10/12-verified pattern).
__device__ inline void stage_km64(const float* __restrict__ src, long ld,
                                  u16* __restrict__ dst, int tid) {
#pragma unroll
    for (int it = 0; it < 4; ++it) {
        const int flat = (it * 256 + tid) * 4;
        const int m = flat & 63, k = flat >> 6;
        const float4 f = *(const float4*)&src[(long)k * ld + m];
        const int cb_ = ((k >> 5) * 4 + (m >> 4)) * 64 + ((k & 31) >> 3) * 16 + (m & 15);
        const int j = k & 7;
        dst[(cb_ + 0) * 8 + j] = f2bf(f.x);
        dst[(cb_ + 1) * 8 + j] = f2bf(f.y);
        dst[(cb_ + 2) * 8 + j] = f2bf(f.z);
        dst[(cb_ + 3) * 8 + j] = f2bf(f.w);
    }
}

// C[m0+..64, n0+..64] (+)= A . B^T, K=256 staged in ONE burst + ONE barrier.
// 4 waves, wave w -> 32x32 at (IA=(w&1)*2, JB=(w>>1)*2) 16-tiles.
// AKM/BKM: operand from K-major f32. BSUM8: B = f32 sum of 8 partials.
// TC: float (plain or atomic) or u16 (bf16 store, non-atomic only).
template <typename TA, typename TB, typename TC,
          bool AKM, bool BKM, bool BSUM8, bool ATOMIC>
__device__ inline void gemm_tile(const TA* __restrict__ A, long lda,
                                 const TB* __restrict__ B, long ldb,
                                 long partStride,
                                 TC* __restrict__ C, long ldc,
                                 int m0, int n0) {
    __shared__ u16 As[16384];   // 32 KB: 4 x 64-k fragment blocks
    __shared__ u16 Bs[16384];
    const int tid = threadIdx.x, lane = tid & 63, w = tid >> 6;
    const int IA = (w & 1) * 2, JB = (w >> 1) * 2;
    floatx4 acc[2][2] = {};

#pragma unroll
    for (int kb = 0; kb < 4; ++kb) {
        if (AKM) stage_km64((const float*)A + (long)(kb * 64) * lda, lda, As + kb * 4096, tid);
        else     stage64(A + kb * 64, lda, As + kb * 4096, tid);
    }
#pragma unroll
    for (int kb = 0; kb < 4; ++kb) {
        if (BSUM8)    stage64_sum8((const float*)B + kb * 64, ldb, partStride, Bs + kb * 4096, tid);
        else if (BKM) stage_km64((const float*)B + (long)(kb * 64) * ldb, ldb, Bs + kb * 4096, tid);
        else          stage64(B + kb * 64, ldb, Bs + kb * 4096, tid);
    }
    __syncthreads();

#pragma unroll
    for (int kb = 0; kb < 4; ++kb)
#pragma unroll
        for (int s = 0; s < 2; ++s) {
            short8 af[2], bfr[2];
#pragma unroll
            for (int i = 0; i < 2; ++i)
                af[i] = *(const short8*)&As[kb * 4096 + ((s * 4 + IA + i) * 64 + lane) * 8];
#pragma unroll
            for (int j = 0; j < 2; ++j)
                bfr[j] = *(const short8*)&Bs[kb * 4096 + ((s * 4 + JB + j) * 64 + lane) * 8];
#pragma unroll
            for (int i = 0; i < 2; ++i)
#pragma unroll
                for (int j = 0; j < 2; ++j)
                    acc[i][j] = __builtin_amdgcn_mfma_f32_16x16x32_bf16(af[i], bfr[j], acc[i][j], 0, 0, 0);
        }

    const int rb = (lane >> 4) * 4, col = lane & 15;
#pragma unroll
    for (int i = 0; i < 2; ++i)
#pragma unroll
        for (int j = 0; j < 2; ++j)
#pragma unroll
            for (int r = 0; r < 4; ++r) {
                const int gm = m0 + (IA + i) * 16 + rb + r;
                const int gn = n0 + (JB + j) * 16 + col;
                TC* p = &C[(long)gm * ldc + gn];
                if (sizeof(TC) == 2) *(u16*)p = f2bf(acc[i][j][r]);
                else if (ATOMIC) atomicAdd((float*)p, acc[i][j][r]);
                else *(float*)p = acc[i][j][r];
            }
}

// gram: Gp[split][bq][f][h] = sum_{u in split} x[b][u][qf] * x[b][u][qh]
// (non-atomic; each block also zeroes its 2KB slice of Wt — consumed two
//  kernels later, stream order guarantees completion/visibility)
__global__ __launch_bounds__(256) void k_gram(const float* __restrict__ x,
                                              float* __restrict__ Gp,
                                              float* __restrict__ Wt) {
    const int tile = blockIdx.x, bq = blockIdx.y, split = blockIdx.z;
    const int tm = tile >> 2, tn = tile & 3;
    const int b = bq >> 2, q = bq & 3;
    {   // zero Wt: 1024 blocks x 512 floats (= 2 MB total)
        const int bl = tile + 16 * bq + 128 * split;
        if (threadIdx.x < 128) {
            const float4 zero = {0.f, 0.f, 0.f, 0.f};
            ((float4*)(Wt + (long)bl * 512))[threadIdx.x] = zero;
        }
    }
    const float* base = x + (long)b * 2097152 + (long)split * 256 * 1024 + q * 256;
    gemm_tile<float, float, float, true, true, false, false>(
        base + tm * 64, 1024,
        base + tn * 64, 1024, 0,
        Gp + (long)(split * 8 + bq) * 65536, 256,
        tm * 64, tn * 64);
}

// 2a: Tt[ba][g][q*256+f] = sum_h comb[a][q*256+h][g] * (sum_s Gp[s][bq])[f][h]
__global__ __launch_bounds__(256) void k_2a(const float* __restrict__ comb,
                                            const float* __restrict__ Gp,
                                            u16* __restrict__ Tt) {
    const int tile = blockIdx.x, i = blockIdx.y;     // i = ba*4+q
    const int tm = tile >> 2, tn = tile & 3;
    const int q = i & 3, ba = i >> 2, b = ba >> 2, a = ba & 3;
    gemm_tile<float, float, u16, true, false, true, false>(
        comb + (long)a * 262144 + (long)q * 256 * 256 + tm * 64, 256,
        Gp + (long)(b * 4 + q) * 65536 + (long)tn * 64 * 256, 256,
        (long)8 * 65536,
        Tt + (long)ba * 262144, 1024,
        tm * 64, q * 256 + tn * 64);
}

// 2b: Wt[ba][g][e] += sum_{k in split} Tt[ba][g][k] * qw[a][e][k]
__global__ __launch_bounds__(256) void k_2b(const u16* __restrict__ Tt,
                                            const float* __restrict__ qw,
                                            float* __restrict__ Wt) {
    const int tile = blockIdx.x, ba = blockIdx.y, split = blockIdx.z;
    const int tm = tile >> 2, tn = tile & 3;
    const int a = ba & 3;
    gemm_tile<u16, float, float, false, false, false, true>(
        Tt + (long)ba * 262144 + (long)tm * 64 * 1024 + split * 256, 1024,
        qw + (long)a * 262144 + (long)tn * 64 * 1024 + split * 256, 1024, 0,
        Wt + (long)ba * 65536, 256,
        tm * 64, tn * 64);
}

// out: out[b][t][a*256+g] = sum_e x[b][t][a*256+e] * Wt[ba][g][e]
__global__ __launch_bounds__(256) void k_3(const float* __restrict__ x,
                                           const float* __restrict__ Wt,
                                           float* __restrict__ out) {
    const int tl = blockIdx.x, ba = blockIdx.y;      // tl: tm 0..31, tn 0..3
    const int tm = tl >> 2, tn = tl & 3;
    const int b = ba >> 2, a = ba & 3;
    gemm_tile<float, float, float, false, false, false, false>(
        x + (long)b * 2097152 + (long)tm * 64 * 1024 + a * 256, 1024,
        Wt + (long)ba * 65536 + (long)tn * 64 * 256, 256, 0,
        out + (long)b * 2097152 + a * 256, 1024,
        tm * 64, tn * 64);
}

extern "C" void kernel_launch(void* const* d_in, const int* in_sizes, int n_in,
                              void* d_out, int out_size, void* d_ws, size_t ws_size,
                              hipStream_t stream) {
    const float* x    = (const float*)d_in[0];   // [2,2048,1024]
    const float* qw   = (const float*)d_in[1];   // [4,256,1024]
    const float* comb = (const float*)d_in[2];   // [4,1024,256]
    float* out = (float*)d_out;

    char* ws = (char*)d_ws;
    float* Gp = (float*)(ws);                    // 16 MB [8 split][8 bq][256x256]
    float* Wt = (float*)(ws + (16u << 20));      // 2 MB  [8][256][256]  Wt[g][e]
    u16*   Tt = (u16*)  (ws + (18u << 20));      // 4 MB  [8][256][1024] Tt[g][qf] bf16

    k_gram<<<dim3(16, 8, 8), 256, 0, stream>>>(x, Gp, Wt);
    k_2a  <<<dim3(16, 32),   256, 0, stream>>>(comb, Gp, Tt);
    k_2b  <<<dim3(16, 8, 4), 256, 0, stream>>>(Tt, qw, Wt);
    k_3   <<<dim3(128, 8),   256, 0, stream>>>(x, Wt, out);
}